// Round 10
// baseline (168.422 us; speedup 1.0000x reference)
//
#include <hip/hip_runtime.h>
#include <cstdint>

// Problem constants (fixed by setup_inputs)
constexpr int kB = 2;
constexpr int kN = 21760;
constexpr int kC = 256;
constexpr int kH = 8;
constexpr int kS = 21760;    // total sample-map area
constexpr int kM = kB * kN;  // 43520 rows
constexpr int kMT = 340;     // m-tiles (kM / 128)

typedef __attribute__((ext_vector_type(8))) short bf16x8;   // MFMA A/B frag (4 VGPR)
typedef __attribute__((ext_vector_type(4))) float f32x4;    // MFMA C/D frag
typedef __attribute__((ext_vector_type(8))) unsigned short us8;

__device__ __forceinline__ float bf2f(unsigned short u) {
  return __uint_as_float(((unsigned int)u) << 16);
}
__device__ __forceinline__ unsigned short f2bf(float f) {
  unsigned int u = __float_as_uint(f);
  u += 0x7fffu + ((u >> 16) & 1u);
  return (unsigned short)(u >> 16);
}
__device__ __forceinline__ float blo(unsigned int v) { return __uint_as_float(v << 16); }
__device__ __forceinline__ float bhi(unsigned int v) { return __uint_as_float(v & 0xffff0000u); }
__device__ __forceinline__ unsigned int cvt_pk_bf16(float lo, float hi) {
  unsigned int r;
  asm("v_cvt_pk_bf16_f32 %0, %1, %2" : "=v"(r) : "v"(lo), "v"(hi));
  return r;   // low ushort = bf16(lo), high ushort = bf16(hi)  [RNE]
}
__device__ __forceinline__ void gld_lds16(const unsigned short* g, unsigned short* l) {
  __builtin_amdgcn_global_load_lds(
      (const __attribute__((address_space(1))) unsigned int*)g,
      (__attribute__((address_space(3))) unsigned int*)l, 16, 0, 0);
}

// ---------------------------------------------------------------------------
// Weight prep only (activation conversion now fused into gemm_lead).
// f32 [K=256][N] -> bf16 transposed [N][K], rows pre-swizzled
// (element k stored at k ^ ((n&7)<<3)).  896 rows * 32 lanes = 112 blocks.
// ---------------------------------------------------------------------------
__global__ __launch_bounds__(256) void prep_weights(
    const float* __restrict__ Woff, const float* __restrict__ Wattn,
    const float* __restrict__ Wval, const float* __restrict__ Wout,
    unsigned short* __restrict__ BtOff, unsigned short* __restrict__ BtAttn,
    unsigned short* __restrict__ BtVal, unsigned short* __restrict__ BtOut)
{
  const int tid = blockIdx.x * 256 + threadIdx.x;
  const int r = tid >> 5;
  const int kb = (tid & 31) * 8;
  const float* W; unsigned short* Bt; int n, Nn;
  if (r < 256)      { W = Woff;  Bt = BtOff;  n = r;       Nn = 256; }
  else if (r < 384) { W = Wattn; Bt = BtAttn; n = r - 256; Nn = 128; }
  else if (r < 640) { W = Wval;  Bt = BtVal;  n = r - 384; Nn = 256; }
  else              { W = Wout;  Bt = BtOut;  n = r - 640; Nn = 256; }
  us8 o;
#pragma unroll
  for (int i = 0; i < 8; ++i) o[i] = f2bf(W[(size_t)(kb + i) * Nn + n]);
  *(us8*)&Bt[(size_t)n * 256 + (kb ^ ((n & 7) << 3))] = o;
}

// ---------------------------------------------------------------------------
// Lead GEMM with fused f32->bf16 A-conversion and m-tile-resident A.
// One block per m-tile per mode: bid < 340 -> mode 0 (A=in_feats, B=BtOA,
// NT=3: cols 0..255 -> off head-major, 256..383 -> attn head-major);
// bid >= 340 -> mode 1 (A=sfeats, B=BtVal, NT=2, out = value head-major).
//
// Prologue (once per block): stage the full 128x256 f32 A-panel as bf16
// into LDS (64 KB, XOR-swizzled rows) — 32 coalesced float4 loads +
// 2x cvt_pk + ds_write per thread. A is read from HBM exactly ONCE per
// m-tile; no intermediate global buffer (round-trip eliminated).
// Inner loop per n-tile per K-step: async global_load_lds B staging +
// MFMA — identical to the proven round-4..7 pipeline.
// LDS 80 KB -> 2 blocks/CU.
// ---------------------------------------------------------------------------
__global__ __launch_bounds__(256) void gemm_lead(
    const float* __restrict__ in_feats,
    const float* __restrict__ sfeats,
    const unsigned short* __restrict__ BtOA,
    const unsigned short* __restrict__ BtVal,
    const float* __restrict__ b_off, const float* __restrict__ b_attn,
    const float* __restrict__ b_val,
    unsigned short* __restrict__ off_hm,
    unsigned short* __restrict__ attn_hm,
    unsigned short* __restrict__ val_hm)
{
  __shared__ unsigned short Afull[4 * 128 * 64];  // 64 KB: [kc][row][64k] swizzled
  __shared__ unsigned short Bs[128 * 64];         // 16 KB

  const int bid = blockIdx.x;
  const int mode = (bid >= kMT) ? 1 : 0;
  const int m = mode ? (bid - kMT) : bid;
  const int m0 = m * 128;
  const int NT = mode ? 2 : 3;
  const unsigned short* Bt = mode ? BtVal : BtOA;

  const int t = threadIdx.x;
  const int w = t >> 6, l = t & 63;
  const int wm = w >> 1, wn = w & 1;

  // ---- prologue: stage A panel f32 -> bf16 swizzled LDS (once) ----
  {
    const int arow = t >> 1;
    const int khalf = (t & 1) * 128;
    const float* Af = (mode ? sfeats : in_feats) + (size_t)(m0 + arow) * 256 + khalf;
    const int swz = (arow & 7) << 3;
#pragma unroll
    for (int i = 0; i < 32; ++i) {
      const int col = khalf + i * 4;
      const float4 f = *(const float4*)&Af[i * 4];
      uint2 o;
      o.x = cvt_pk_bf16(f.x, f.y);
      o.y = cvt_pk_bf16(f.z, f.w);
      *(uint2*)&Afull[(col >> 6) * 8192 + arow * 64 + ((col & 63) ^ swz)] = o;
    }
  }

  // B staging mapping (per K-step)
  const int srow = l >> 3;
  const int skb  = (l & 7) * 8;
  const int lr = l >> 4;

  for (int nt = 0; nt < NT; ++nt) {
    const int n0 = nt * 128;
    f32x4 acc[4][4] = {};

    for (int kt = 0; kt < 256; kt += 64) {
#pragma unroll
      for (int i = 0; i < 4; ++i) {
        const int c = i * 4 + w;
        const int row = c * 8 + srow;
        gld_lds16(Bt + (size_t)(n0 + row) * 256 + kt + skb, &Bs[c * 512]);
      }
      __syncthreads();   // drains vmcnt (B landed) + A-stage visible (1st iter)

      const int kc = kt >> 6;
#pragma unroll
      for (int s = 0; s < 2; ++s) {
        bf16x8 afr[4], bfr[4];
        const int kf = s * 32 + ((l >> 4) * 8);
#pragma unroll
        for (int i = 0; i < 4; ++i) {
          const int row = wm * 64 + i * 16 + (l & 15);
          afr[i] = *(const bf16x8*)&Afull[kc * 8192 + row * 64 + (kf ^ ((row & 7) << 3))];
        }
#pragma unroll
        for (int j = 0; j < 4; ++j) {
          const int col = wn * 64 + j * 16 + (l & 15);
          bfr[j] = *(const bf16x8*)&Bs[col * 64 + (kf ^ ((col & 7) << 3))];
        }
#pragma unroll
        for (int i = 0; i < 4; ++i)
#pragma unroll
          for (int j = 0; j < 4; ++j)
            acc[i][j] = __builtin_amdgcn_mfma_f32_16x16x32_bf16(afr[i], bfr[j], acc[i][j], 0, 0, 0);
      }
      __syncthreads();   // all Bs reads done before next staging
    }

    // epilogue for this n-tile: C/D map col = lane&15, row = (lane>>4)*4 + reg
#pragma unroll
    for (int j = 0; j < 4; ++j) {
      const int col = n0 + wn * 64 + j * 16 + (l & 15);
      const float bv = mode ? b_val[col] : (col < 256 ? b_off[col] : b_attn[col - 256]);
#pragma unroll
      for (int i = 0; i < 4; ++i) {
        const int rbase = m0 + wm * 64 + i * 16 + lr * 4;
#pragma unroll
        for (int r = 0; r < 4; ++r) {
          const float v = acc[i][j][r] + bv;
          const int row = rbase + r;
          if (mode == 1) {          // value head-major [16][kS][32]
            const int bb = row >= kS;
            const int s2 = row - bb * kS;
            val_hm[((size_t)(bb * 8 + (col >> 5)) * kS + s2) * 32 + (col & 31)] = f2bf(v);
          } else if (col < 256) {   // off head-major [8][kM][32]
            off_hm[((size_t)(col >> 5) * kM + row) * 32 + (col & 31)] = f2bf(v);
          } else {                  // attn head-major [8][kM][16]
            const int c2 = col - 256;
            attn_hm[((size_t)(c2 >> 4) * kM + row) * 16 + (c2 & 15)] = f2bf(v);
          }
        }
      }
    }
  }
}

// ---------------------------------------------------------------------------
// Output GEMM (unchanged — proven; wgt is bf16 row-swizzled by msda).
// ---------------------------------------------------------------------------
__device__ __forceinline__ void mfma_tile_256(
    const unsigned short* __restrict__ A, const unsigned short* __restrict__ Bt,
    int m0, int n0, int t, unsigned short* As, unsigned short* Bs,
    f32x4 (&acc)[4][4])
{
  const int w = t >> 6, l = t & 63;
  const int wm = w >> 1, wn = w & 1;
  const int srow = l >> 3;
  const int skb  = (l & 7) * 8;

  for (int kt = 0; kt < 256; kt += 64) {
#pragma unroll
    for (int i = 0; i < 4; ++i) {
      const int c = i * 4 + w;
      const int row = c * 8 + srow;
      gld_lds16(A + (size_t)(m0 + row) * 256 + kt + skb, &As[c * 512]);
    }
#pragma unroll
    for (int i = 0; i < 4; ++i) {
      const int c = i * 4 + w;
      const int row = c * 8 + srow;
      gld_lds16(Bt + (size_t)(n0 + row) * 256 + kt + skb, &Bs[c * 512]);
    }
    __syncthreads();

#pragma unroll
    for (int s = 0; s < 2; ++s) {
      bf16x8 afr[4], bfr[4];
      const int kf = s * 32 + ((l >> 4) * 8);
#pragma unroll
      for (int i = 0; i < 4; ++i) {
        const int row = wm * 64 + i * 16 + (l & 15);
        afr[i] = *(const bf16x8*)&As[row * 64 + (kf ^ ((row & 7) << 3))];
      }
#pragma unroll
      for (int j = 0; j < 4; ++j) {
        const int col = wn * 64 + j * 16 + (l & 15);
        bfr[j] = *(const bf16x8*)&Bs[col * 64 + (kf ^ ((col & 7) << 3))];
      }
#pragma unroll
      for (int i = 0; i < 4; ++i)
#pragma unroll
        for (int j = 0; j < 4; ++j)
          acc[i][j] = __builtin_amdgcn_mfma_f32_16x16x32_bf16(afr[i], bfr[j], acc[i][j], 0, 0, 0);
    }
    __syncthreads();
  }
}

__global__ __launch_bounds__(256) void gemm_out(
    const unsigned short* __restrict__ wgt,
    const unsigned short* __restrict__ BtOut,
    const float* __restrict__ b_out,
    float* __restrict__ out)
{
  const int bid = blockIdx.x;
  const int x = bid & 7;
  const int slot = bid >> 3;
  const int nt = slot % 2;
  const int mh = slot / 2;
  const int m = mh * 8 + x;
  if (m >= kMT) return;
  const int m0 = m * 128, n0 = nt * 128;

  __shared__ unsigned short As[128 * 64];
  __shared__ unsigned short Bs[128 * 64];
  const int t = threadIdx.x;

  f32x4 acc[4][4] = {};
  mfma_tile_256(wgt, BtOut, m0, n0, t, As, Bs, acc);

  const int w = t >> 6, l = t & 63;
  const int wm = w >> 1, wn = w & 1;
  const int lr = l >> 4;
#pragma unroll
  for (int j = 0; j < 4; ++j) {
    const int col = n0 + wn * 64 + j * 16 + (l & 15);
    const float bv = b_out[col];
#pragma unroll
    for (int i = 0; i < 4; ++i) {
      const int rbase = m0 + wm * 64 + i * 16 + lr * 4;
#pragma unroll
      for (int r = 0; r < 4; ++r)
        out[(size_t)(rbase + r) * 256 + col] = acc[i][j][r] + bv;
    }
  }
}

// ---------------------------------------------------------------------------
// MSDA core — ROUND-7 VERBATIM (measured 72.2 us; proven correct).
// Plane-partitioned: block = 16 queries x one (b,h) plane; plane p's blocks
// land on XCD p&7 -> value working set L2-resident.
// ---------------------------------------------------------------------------
__global__ __launch_bounds__(256, 4) void msda_kernel(
    const unsigned short* __restrict__ off_hm,   // [8][kM][32] bf16 head-major
    const unsigned short* __restrict__ attn_hm,  // [8][kM][16] bf16 head-major
    const unsigned short* __restrict__ val_bf,   // [16][kS][32] bf16 head-major
    const float* __restrict__ priors,            // [kM][8]
    unsigned short* __restrict__ wgt)            // [kM][256] bf16 swizzled
{
  __shared__ int s_rec[16 * 136];
  const int bid = blockIdx.x;
  const int plane = bid & 15;          // b*8 + h
  const int chunk = bid >> 4;
  const int b = plane >> 3, h = plane & 7;
  const int t = threadIdx.x;
  const int ql = t >> 4;
  const int q = b * kN + chunk * 16 + ql;

  { // ---- phase 1 ----
    const int j = t & 15;
    const int lv = j >> 2;

    const float lgt = bf2f(attn_hm[((size_t)h * kM + q) * 16 + j]);
    float mx = lgt;
#pragma unroll
    for (int m = 8; m; m >>= 1) mx = fmaxf(mx, __shfl_xor(mx, m, 16));
    const float p = __expf(lgt - mx);
    float sum = p;
#pragma unroll
    for (int m = 8; m; m >>= 1) sum += __shfl_xor(sum, m, 16);
    const float wN = p / sum;

    const unsigned int oo = *(const unsigned int*)&off_hm[((size_t)h * kM + q) * 32 + j * 2];
    const float ox = blo(oo);
    const float oy = bhi(oo);
    const float2 pr = *(const float2*)&priors[(size_t)q * 8 + lv * 2];

    const int Wl = 128 >> lv;
    const float fW = (float)Wl;
    const float lx = fmaf(pr.x, fW, ox) - 0.5f;
    const float ly = fmaf(pr.y, fW, oy) - 0.5f;
    const float x0f = floorf(lx), y0f = floorf(ly);
    const float wx1 = lx - x0f, wy1 = ly - y0f;
    const float wx0 = 1.f - wx1, wy0 = 1.f - wy1;
    const int x0 = (int)x0f, y0 = (int)y0f;
    const int start = (int)((0x5400500040000000ull >> (16 * lv)) & 0xffff); // {0,16384,20480,21504}

    const bool vx0 = (x0 >= 0) & (x0 < Wl);
    const bool vx1 = (x0 + 1 >= 0) & (x0 + 1 < Wl);
    const bool vy0 = (y0 >= 0) & (y0 < Wl);
    const bool vy1 = (y0 + 1 >= 0) & (y0 + 1 < Wl);
    const int xc0 = min(max(x0, 0), Wl - 1);
    const int xc1 = min(max(x0 + 1, 0), Wl - 1);
    const int yc0 = min(max(y0, 0), Wl - 1);
    const int yc1 = min(max(y0 + 1, 0), Wl - 1);

    const int rt = start + yc0 * Wl;   // row bases (elements)
    const int rb = start + yc1 * Wl;

    int4 r0, r1;
    r0.x = (rt + xc0) * 64; r0.y = __float_as_int((vx0 & vy0) ? wN * wx0 * wy0 : 0.f);
    r0.z = (rt + xc1) * 64; r0.w = __float_as_int((vx1 & vy0) ? wN * wx1 * wy0 : 0.f);
    r1.x = (rb + xc0) * 64; r1.y = __float_as_int((vx0 & vy1) ? wN * wx0 * wy1 : 0.f);
    r1.z = (rb + xc1) * 64; r1.w = __float_as_int((vx1 & vy1) ? wN * wx1 * wy1 : 0.f);

    const int base = ql * 136 + j * 8;
    *(int4*)&s_rec[base] = r0;
    *(int4*)&s_rec[base + 4] = r1;
  }
  __syncthreads();

  // ---- phase 2 (MLP-batched, compiler-scheduled) ----
  const int lane = t & 15;
  const int c = lane >> 2;        // corner: 0=TL 1=TR 2=BL 3=BR
  const int k = lane & 3;         // 16B chunk (8 channels)
  const char* plane_base = (const char*)val_bf + (size_t)plane * kS * 64 + k * 16;
  const int* rp = &s_rec[ql * 136 + c * 2];

  float a0 = 0.f, a1 = 0.f, a2 = 0.f, a3 = 0.f;
  float a4 = 0.f, a5 = 0.f, a6 = 0.f, a7 = 0.f;
#pragma unroll
  for (int B = 0; B < 2; ++B) {
    int2 r[8];
#pragma unroll
    for (int j = 0; j < 8; ++j) r[j] = *(const int2*)&rp[(B * 8 + j) * 8];
    uint4 v[8];
#pragma unroll
    for (int j = 0; j < 8; ++j) v[j] = *(const uint4*)(plane_base + r[j].x);
#pragma unroll
    for (int j = 0; j < 8; ++j) {
      const float w = __int_as_float(r[j].y);
      a0 = fmaf(w, blo(v[j].x), a0); a1 = fmaf(w, bhi(v[j].x), a1);
      a2 = fmaf(w, blo(v[j].y), a2); a3 = fmaf(w, bhi(v[j].y), a3);
      a4 = fmaf(w, blo(v[j].z), a4); a5 = fmaf(w, bhi(v[j].z), a5);
      a6 = fmaf(w, blo(v[j].w), a6); a7 = fmaf(w, bhi(v[j].w), a7);
    }
  }

  // fold the 4 corners (lane bits 2-3)
#pragma unroll
  for (int m = 4; m <= 8; m <<= 1) {
    a0 += __shfl_xor(a0, m); a1 += __shfl_xor(a1, m);
    a2 += __shfl_xor(a2, m); a3 += __shfl_xor(a3, m);
    a4 += __shfl_xor(a4, m); a5 += __shfl_xor(a5, m);
    a6 += __shfl_xor(a6, m); a7 += __shfl_xor(a7, m);
  }

  if (c == 0) {
    const int c0 = h * 32 + k * 8;                    // ushort index in row
    const int dst = c0 ^ ((q & 7) << 3);
    uint4 o;
    o.x = cvt_pk_bf16(a0, a1);
    o.y = cvt_pk_bf16(a2, a3);
    o.z = cvt_pk_bf16(a4, a5);
    o.w = cvt_pk_bf16(a6, a7);
    *(uint4*)&wgt[(size_t)q * 256 + dst] = o;
  }
}

// ---------------------------------------------------------------------------
// launch
// ---------------------------------------------------------------------------
extern "C" void kernel_launch(void* const* d_in, const int* in_sizes, int n_in,
                              void* d_out, int out_size, void* d_ws, size_t ws_size,
                              hipStream_t stream) {
  const float* in_feats = (const float*)d_in[0];
  const float* priors   = (const float*)d_in[1];
  const float* sfeats   = (const float*)d_in[2];
  const float* W_off  = (const float*)d_in[5];
  const float* b_off  = (const float*)d_in[6];
  const float* W_attn = (const float*)d_in[7];
  const float* b_attn = (const float*)d_in[8];
  const float* W_val  = (const float*)d_in[9];
  const float* b_val  = (const float*)d_in[10];
  const float* W_out  = (const float*)d_in[11];
  const float* b_out  = (const float*)d_in[12];
  float* out = (float*)d_out;

  // workspace (bf16 ushorts), ~45 MB
  unsigned short* off_hm  = (unsigned short*)d_ws;          // [8][kM][32]
  unsigned short* attn_hm = off_hm  + (size_t)kM * 256;     // [8][kM][16]
  unsigned short* val_hm  = attn_hm + (size_t)kM * 128;     // [16][kS][32]
  unsigned short* wgt_bf  = val_hm  + (size_t)kM * 256;     // [kM][256] swizzled
  unsigned short* BtOff   = wgt_bf  + (size_t)kM * 256;     // 256*256 (BtOA rows 0-255)
  unsigned short* BtAttn  = BtOff   + 256 * 256;            // 128*256 (BtOA rows 256-383)
  unsigned short* BtVal   = BtAttn  + 128 * 256;            // 256*256
  unsigned short* BtOut   = BtVal   + 256 * 256;            // 256*256

  const dim3 blk(256);

  prep_weights<<<dim3(112), blk, 0, stream>>>(
      W_off, W_attn, W_val, W_out, BtOff, BtAttn, BtVal, BtOut);

  gemm_lead<<<dim3(2 * kMT), blk, 0, stream>>>(
      in_feats, sfeats, BtOff, BtVal, b_off, b_attn, b_val,
      off_hm, attn_hm, val_hm);

  msda_kernel<<<dim3(kM / 2), blk, 0, stream>>>(off_hm, attn_hm, val_hm, priors, wgt_bf);

  gemm_out<<<dim3(8 * 2 * 43), blk, 0, stream>>>(wgt_bf, BtOut, b_out, out);
}

// Round 11
// 166.520 us; speedup vs baseline: 1.0114x; 1.0114x over previous
//
#include <hip/hip_runtime.h>
#include <cstdint>

// Problem constants (fixed by setup_inputs)
constexpr int kB = 2;
constexpr int kN = 21760;
constexpr int kC = 256;
constexpr int kH = 8;
constexpr int kS = 21760;    // total sample-map area
constexpr int kM = kB * kN;  // 43520 rows
constexpr int kMT = 340;     // m-tiles (kM / 128)

typedef __attribute__((ext_vector_type(8))) short bf16x8;   // MFMA A/B frag (4 VGPR)
typedef __attribute__((ext_vector_type(4))) float f32x4;    // MFMA C/D frag
typedef __attribute__((ext_vector_type(8))) unsigned short us8;

__device__ __forceinline__ float bf2f(unsigned short u) {
  return __uint_as_float(((unsigned int)u) << 16);
}
__device__ __forceinline__ unsigned short f2bf(float f) {
  unsigned int u = __float_as_uint(f);
  u += 0x7fffu + ((u >> 16) & 1u);
  return (unsigned short)(u >> 16);
}
__device__ __forceinline__ float blo(unsigned int v) { return __uint_as_float(v << 16); }
__device__ __forceinline__ float bhi(unsigned int v) { return __uint_as_float(v & 0xffff0000u); }
__device__ __forceinline__ unsigned int cvt_pk_bf16(float lo, float hi) {
  unsigned int r;
  asm("v_cvt_pk_bf16_f32 %0, %1, %2" : "=v"(r) : "v"(lo), "v"(hi));
  return r;   // low ushort = bf16(lo), high ushort = bf16(hi)  [RNE]
}
__device__ __forceinline__ void gld_lds16(const unsigned short* g, unsigned short* l) {
  __builtin_amdgcn_global_load_lds(
      (const __attribute__((address_space(1))) unsigned int*)g,
      (__attribute__((address_space(3))) unsigned int*)l, 16, 0, 0);
}

// ---------------------------------------------------------------------------
// Fused convert + weight prep (round-7 verbatim — proven).
// ---------------------------------------------------------------------------
__global__ __launch_bounds__(256) void convprep(
    const float* __restrict__ a, const float* __restrict__ b,
    unsigned short* __restrict__ da, unsigned short* __restrict__ db,
    const float* __restrict__ Woff, const float* __restrict__ Wattn,
    const float* __restrict__ Wval, const float* __restrict__ Wout,
    unsigned short* __restrict__ BtOff, unsigned short* __restrict__ BtAttn,
    unsigned short* __restrict__ BtVal, unsigned short* __restrict__ BtOut)
{
  const int bid = blockIdx.x;
  if (bid < 10880) {
    const int tid = bid * 256 + threadIdx.x;
    const int half = kM * 32;
    const float* src; unsigned short* dst; int id;
    if (tid < half) { src = a; dst = da; id = tid; }
    else            { src = b; dst = db; id = tid - half; }
    const int m = id >> 5;
    const int kb = (id & 31) * 8;
    const float4 x0 = *(const float4*)&src[(size_t)m * 256 + kb];
    const float4 x1 = *(const float4*)&src[(size_t)m * 256 + kb + 4];
    us8 o;
    o[0] = f2bf(x0.x); o[1] = f2bf(x0.y); o[2] = f2bf(x0.z); o[3] = f2bf(x0.w);
    o[4] = f2bf(x1.x); o[5] = f2bf(x1.y); o[6] = f2bf(x1.z); o[7] = f2bf(x1.w);
    *(us8*)&dst[(size_t)m * 256 + (kb ^ ((m & 7) << 3))] = o;
  } else {
    const int tid = (bid - 10880) * 256 + threadIdx.x;   // 896 rows * 32
    const int r = tid >> 5;
    const int kb = (tid & 31) * 8;
    const float* W; unsigned short* Bt; int n, Nn;
    if (r < 256)      { W = Woff;  Bt = BtOff;  n = r;       Nn = 256; }
    else if (r < 384) { W = Wattn; Bt = BtAttn; n = r - 256; Nn = 128; }
    else if (r < 640) { W = Wval;  Bt = BtVal;  n = r - 384; Nn = 256; }
    else              { W = Wout;  Bt = BtOut;  n = r - 640; Nn = 256; }
    us8 o;
#pragma unroll
    for (int i = 0; i < 8; ++i) o[i] = f2bf(W[(size_t)(kb + i) * Nn + n]);
    *(us8*)&Bt[(size_t)n * 256 + (kb ^ ((n & 7) << 3))] = o;
  }
}

// ---------------------------------------------------------------------------
// Shared MFMA tile core (round-7 verbatim — proven).
// ---------------------------------------------------------------------------
__device__ __forceinline__ void mfma_tile_256(
    const unsigned short* __restrict__ A, const unsigned short* __restrict__ Bt,
    int m0, int n0, int t, unsigned short* As, unsigned short* Bs,
    f32x4 (&acc)[4][4])
{
  const int w = t >> 6, l = t & 63;
  const int wm = w >> 1, wn = w & 1;
  const int srow = l >> 3;
  const int skb  = (l & 7) * 8;

  for (int kt = 0; kt < 256; kt += 64) {
#pragma unroll
    for (int i = 0; i < 4; ++i) {
      const int c = i * 4 + w;
      const int row = c * 8 + srow;
      gld_lds16(A + (size_t)(m0 + row) * 256 + kt + skb, &As[c * 512]);
    }
#pragma unroll
    for (int i = 0; i < 4; ++i) {
      const int c = i * 4 + w;
      const int row = c * 8 + srow;
      gld_lds16(Bt + (size_t)(n0 + row) * 256 + kt + skb, &Bs[c * 512]);
    }
    __syncthreads();

#pragma unroll
    for (int s = 0; s < 2; ++s) {
      bf16x8 afr[4], bfr[4];
      const int kf = s * 32 + ((l >> 4) * 8);
#pragma unroll
      for (int i = 0; i < 4; ++i) {
        const int row = wm * 64 + i * 16 + (l & 15);
        afr[i] = *(const bf16x8*)&As[row * 64 + (kf ^ ((row & 7) << 3))];
      }
#pragma unroll
      for (int j = 0; j < 4; ++j) {
        const int col = wn * 64 + j * 16 + (l & 15);
        bfr[j] = *(const bf16x8*)&Bs[col * 64 + (kf ^ ((col & 7) << 3))];
      }
#pragma unroll
      for (int i = 0; i < 4; ++i)
#pragma unroll
        for (int j = 0; j < 4; ++j)
          acc[i][j] = __builtin_amdgcn_mfma_f32_16x16x32_bf16(afr[i], bfr[j], acc[i][j], 0, 0, 0);
    }
    __syncthreads();
  }
}

// ---------------------------------------------------------------------------
// Lead GEMM (round-7 verbatim — proven).
// ---------------------------------------------------------------------------
__global__ __launch_bounds__(256) void gemm_lead(
    const unsigned short* __restrict__ in_bf,
    const unsigned short* __restrict__ s_bf,
    const unsigned short* __restrict__ BtOA,
    const unsigned short* __restrict__ BtVal,
    const float* __restrict__ b_off, const float* __restrict__ b_attn,
    const float* __restrict__ b_val,
    unsigned short* __restrict__ off_hm,
    unsigned short* __restrict__ attn_hm,
    unsigned short* __restrict__ val_hm)
{
  const int bid = blockIdx.x;
  const int x = bid & 7;
  const int slot = bid >> 3;
  int mode, nt, mh;
  if (slot < 129) { mode = 0; nt = slot % 3; mh = slot / 3; }
  else            { mode = 1; const int s2 = slot - 129; nt = s2 % 2; mh = s2 / 2; }
  const int m = mh * 8 + x;
  if (m >= kMT) return;
  const int m0 = m * 128, n0 = nt * 128;

  __shared__ unsigned short As[128 * 64];
  __shared__ unsigned short Bs[128 * 64];
  const int t = threadIdx.x;

  f32x4 acc[4][4] = {};
  mfma_tile_256(mode ? s_bf : in_bf, mode ? BtVal : BtOA, m0, n0, t, As, Bs, acc);

  const int w = t >> 6, l = t & 63;
  const int wm = w >> 1, wn = w & 1;
  const int lr = l >> 4;
#pragma unroll
  for (int j = 0; j < 4; ++j) {
    const int col = n0 + wn * 64 + j * 16 + (l & 15);
    const float bv = mode ? b_val[col] : (col < 256 ? b_off[col] : b_attn[col - 256]);
#pragma unroll
    for (int i = 0; i < 4; ++i) {
      const int rbase = m0 + wm * 64 + i * 16 + lr * 4;
#pragma unroll
      for (int r = 0; r < 4; ++r) {
        const float v = acc[i][j][r] + bv;
        const int row = rbase + r;
        if (mode == 1) {          // value head-major [16][kS][32]
          const int bb = row >= kS;
          const int s2 = row - bb * kS;
          val_hm[((size_t)(bb * 8 + (col >> 5)) * kS + s2) * 32 + (col & 31)] = f2bf(v);
        } else if (col < 256) {   // off head-major [8][kM][32]
          off_hm[((size_t)(col >> 5) * kM + row) * 32 + (col & 31)] = f2bf(v);
        } else {                  // attn head-major [8][kM][16]
          const int c2 = col - 256;
          attn_hm[((size_t)(c2 >> 4) * kM + row) * 16 + (c2 & 15)] = f2bf(v);
        }
      }
    }
  }
}

// ---------------------------------------------------------------------------
// Output GEMM (round-7 verbatim — proven).
// ---------------------------------------------------------------------------
__global__ __launch_bounds__(256) void gemm_out(
    const unsigned short* __restrict__ wgt,
    const unsigned short* __restrict__ BtOut,
    const float* __restrict__ b_out,
    float* __restrict__ out)
{
  const int bid = blockIdx.x;
  const int x = bid & 7;
  const int slot = bid >> 3;
  const int nt = slot % 2;
  const int mh = slot / 2;
  const int m = mh * 8 + x;
  if (m >= kMT) return;
  const int m0 = m * 128, n0 = nt * 128;

  __shared__ unsigned short As[128 * 64];
  __shared__ unsigned short Bs[128 * 64];
  const int t = threadIdx.x;

  f32x4 acc[4][4] = {};
  mfma_tile_256(wgt, BtOut, m0, n0, t, As, Bs, acc);

  const int w = t >> 6, l = t & 63;
  const int wm = w >> 1, wn = w & 1;
  const int lr = l >> 4;
#pragma unroll
  for (int j = 0; j < 4; ++j) {
    const int col = n0 + wn * 64 + j * 16 + (l & 15);
    const float bv = b_out[col];
#pragma unroll
    for (int i = 0; i < 4; ++i) {
      const int rbase = m0 + wm * 64 + i * 16 + lr * 4;
#pragma unroll
      for (int r = 0; r < 4; ++r)
        out[(size_t)(rbase + r) * 256 + col] = acc[i][j][r] + bv;
    }
  }
}

// ---------------------------------------------------------------------------
// MSDA core, plane-partitioned. A/B experiment vs round-7: block = 8
// queries x one (b,h) plane, 32 lanes per (q,h): sh = sample-half (2),
// c = corner (4), k = 16B chunk (4). Each thread gathers 8 samples
// (vs 16) -> per-thread dependent-load chain halves at unchanged TLP
// (same 4 waves/block, VGPR small, LDS 4.4KB). One extra shfl_xor(16)
// folds the sample halves. Decision rule: msda drops -> latency-bound
// (keep pushing); flat -> VALU-bound floor (stop).
// ---------------------------------------------------------------------------
__global__ __launch_bounds__(256, 4) void msda_kernel(
    const unsigned short* __restrict__ off_hm,   // [8][kM][32] bf16 head-major
    const unsigned short* __restrict__ attn_hm,  // [8][kM][16] bf16 head-major
    const unsigned short* __restrict__ val_bf,   // [16][kS][32] bf16 head-major
    const float* __restrict__ priors,            // [kM][8]
    unsigned short* __restrict__ wgt)            // [kM][256] bf16 swizzled
{
  __shared__ int s_rec[8 * 136];
  const int bid = blockIdx.x;
  const int plane = bid & 15;          // b*8 + h
  const int chunk = bid >> 4;          // 0..kN/8-1
  const int b = plane >> 3, h = plane & 7;
  const int t = threadIdx.x;

  if (t < 128) { // ---- phase 1: 8 q x 16 samples ----
    const int ql = t >> 4;
    const int j = t & 15;
    const int q = b * kN + chunk * 8 + ql;
    const int lv = j >> 2;

    const float lgt = bf2f(attn_hm[((size_t)h * kM + q) * 16 + j]);
    float mx = lgt;
#pragma unroll
    for (int m = 8; m; m >>= 1) mx = fmaxf(mx, __shfl_xor(mx, m, 16));
    const float p = __expf(lgt - mx);
    float sum = p;
#pragma unroll
    for (int m = 8; m; m >>= 1) sum += __shfl_xor(sum, m, 16);
    const float wN = p / sum;

    const unsigned int oo = *(const unsigned int*)&off_hm[((size_t)h * kM + q) * 32 + j * 2];
    const float ox = blo(oo);
    const float oy = bhi(oo);
    const float2 pr = *(const float2*)&priors[(size_t)q * 8 + lv * 2];

    const int Wl = 128 >> lv;
    const float fW = (float)Wl;
    const float lx = fmaf(pr.x, fW, ox) - 0.5f;
    const float ly = fmaf(pr.y, fW, oy) - 0.5f;
    const float x0f = floorf(lx), y0f = floorf(ly);
    const float wx1 = lx - x0f, wy1 = ly - y0f;
    const float wx0 = 1.f - wx1, wy0 = 1.f - wy1;
    const int x0 = (int)x0f, y0 = (int)y0f;
    const int start = (int)((0x5400500040000000ull >> (16 * lv)) & 0xffff); // {0,16384,20480,21504}

    const bool vx0 = (x0 >= 0) & (x0 < Wl);
    const bool vx1 = (x0 + 1 >= 0) & (x0 + 1 < Wl);
    const bool vy0 = (y0 >= 0) & (y0 < Wl);
    const bool vy1 = (y0 + 1 >= 0) & (y0 + 1 < Wl);
    const int xc0 = min(max(x0, 0), Wl - 1);
    const int xc1 = min(max(x0 + 1, 0), Wl - 1);
    const int yc0 = min(max(y0, 0), Wl - 1);
    const int yc1 = min(max(y0 + 1, 0), Wl - 1);

    const int rt = start + yc0 * Wl;   // row bases (elements)
    const int rb = start + yc1 * Wl;

    int4 r0, r1;
    r0.x = (rt + xc0) * 64; r0.y = __float_as_int((vx0 & vy0) ? wN * wx0 * wy0 : 0.f);
    r0.z = (rt + xc1) * 64; r0.w = __float_as_int((vx1 & vy0) ? wN * wx1 * wy0 : 0.f);
    r1.x = (rb + xc0) * 64; r1.y = __float_as_int((vx0 & vy1) ? wN * wx0 * wy1 : 0.f);
    r1.z = (rb + xc1) * 64; r1.w = __float_as_int((vx1 & vy1) ? wN * wx1 * wy1 : 0.f);

    const int base = ql * 136 + j * 8;
    *(int4*)&s_rec[base] = r0;
    *(int4*)&s_rec[base + 4] = r1;
  }
  __syncthreads();

  // ---- phase 2: 32 lanes per q; each thread 8 samples ----
  const int ql = t >> 5;
  const int q = b * kN + chunk * 8 + ql;
  const int lane = t & 31;
  const int sh = lane >> 4;       // sample half: 0 -> j 0..7, 1 -> j 8..15
  const int c = (lane >> 2) & 3;  // corner: 0=TL 1=TR 2=BL 3=BR
  const int k = lane & 3;         // 16B chunk (8 channels)
  const char* plane_base = (const char*)val_bf + (size_t)plane * kS * 64 + k * 16;
  const int* rp = &s_rec[ql * 136 + c * 2];

  float a0 = 0.f, a1 = 0.f, a2 = 0.f, a3 = 0.f;
  float a4 = 0.f, a5 = 0.f, a6 = 0.f, a7 = 0.f;
  {
    int2 r[8];
#pragma unroll
    for (int j = 0; j < 8; ++j) r[j] = *(const int2*)&rp[(sh * 8 + j) * 8];
    uint4 v[8];
#pragma unroll
    for (int j = 0; j < 8; ++j) v[j] = *(const uint4*)(plane_base + r[j].x);
#pragma unroll
    for (int j = 0; j < 8; ++j) {
      const float w = __int_as_float(r[j].y);
      a0 = fmaf(w, blo(v[j].x), a0); a1 = fmaf(w, bhi(v[j].x), a1);
      a2 = fmaf(w, blo(v[j].y), a2); a3 = fmaf(w, bhi(v[j].y), a3);
      a4 = fmaf(w, blo(v[j].z), a4); a5 = fmaf(w, bhi(v[j].z), a5);
      a6 = fmaf(w, blo(v[j].w), a6); a7 = fmaf(w, bhi(v[j].w), a7);
    }
  }

  // fold corners (lane bits 2-3) then sample halves (lane bit 4)
#pragma unroll
  for (int m = 4; m <= 16; m <<= 1) {
    a0 += __shfl_xor(a0, m); a1 += __shfl_xor(a1, m);
    a2 += __shfl_xor(a2, m); a3 += __shfl_xor(a3, m);
    a4 += __shfl_xor(a4, m); a5 += __shfl_xor(a5, m);
    a6 += __shfl_xor(a6, m); a7 += __shfl_xor(a7, m);
  }

  if ((lane & 28) == 0) {   // c == 0 && sh == 0: 4 k-lanes per q write
    const int c0 = h * 32 + k * 8;                    // ushort index in row
    const int dst = c0 ^ ((q & 7) << 3);
    uint4 o;
    o.x = cvt_pk_bf16(a0, a1);
    o.y = cvt_pk_bf16(a2, a3);
    o.z = cvt_pk_bf16(a4, a5);
    o.w = cvt_pk_bf16(a6, a7);
    *(uint4*)&wgt[(size_t)q * 256 + dst] = o;
  }
}

// ---------------------------------------------------------------------------
// launch
// ---------------------------------------------------------------------------
extern "C" void kernel_launch(void* const* d_in, const int* in_sizes, int n_in,
                              void* d_out, int out_size, void* d_ws, size_t ws_size,
                              hipStream_t stream) {
  const float* in_feats = (const float*)d_in[0];
  const float* priors   = (const float*)d_in[1];
  const float* sfeats   = (const float*)d_in[2];
  const float* W_off  = (const float*)d_in[5];
  const float* b_off  = (const float*)d_in[6];
  const float* W_attn = (const float*)d_in[7];
  const float* b_attn = (const float*)d_in[8];
  const float* W_val  = (const float*)d_in[9];
  const float* b_val  = (const float*)d_in[10];
  const float* W_out  = (const float*)d_in[11];
  const float* b_out  = (const float*)d_in[12];
  float* out = (float*)d_out;

  // workspace (bf16 ushorts), ~123 MB
  unsigned short* in_bf   = (unsigned short*)d_ws;          // kM*256 (swizzled)
  unsigned short* s_bf    = in_bf   + (size_t)kM * 256;     // kM*256 (swizzled)
  unsigned short* off_hm  = s_bf    + (size_t)kM * 256;     // [8][kM][32]
  unsigned short* attn_hm = off_hm  + (size_t)kM * 256;     // [8][kM][16]
  unsigned short* val_hm  = attn_hm + (size_t)kM * 128;     // [16][kS][32]
  unsigned short* wgt_bf  = val_hm  + (size_t)kM * 256;     // [kM][256] swizzled
  unsigned short* BtOff   = wgt_bf  + (size_t)kM * 256;     // 256*256 (BtOA rows 0-255)
  unsigned short* BtAttn  = BtOff   + 256 * 256;            // 128*256 (BtOA rows 256-383)
  unsigned short* BtVal   = BtAttn  + 128 * 256;            // 256*256
  unsigned short* BtOut   = BtVal   + 256 * 256;            // 256*256

  const dim3 blk(256);

  convprep<<<dim3(10992), blk, 0, stream>>>(
      in_feats, sfeats, in_bf, s_bf,
      W_off, W_attn, W_val, W_out, BtOff, BtAttn, BtVal, BtOut);

  gemm_lead<<<dim3(8 * 215), blk, 0, stream>>>(
      in_bf, s_bf, BtOff, BtVal, b_off, b_attn, b_val, off_hm, attn_hm, val_hm);

  msda_kernel<<<dim3((kN / 8) * 16), blk, 0, stream>>>(off_hm, attn_hm, val_hm, priors, wgt_bf);

  gemm_out<<<dim3(8 * 2 * 43), blk, 0, stream>>>(wgt_bf, BtOut, b_out, out);
}

// Round 12
// 145.587 us; speedup vs baseline: 1.1569x; 1.1438x over previous
//
#include <hip/hip_runtime.h>
#include <cstdint>

// Problem constants (fixed by setup_inputs)
constexpr int kB = 2;
constexpr int kN = 21760;
constexpr int kC = 256;
constexpr int kH = 8;
constexpr int kS = 21760;    // total sample-map area
constexpr int kM = kB * kN;  // 43520 rows
constexpr int kMT = 340;     // m-tiles (kM / 128)

typedef __attribute__((ext_vector_type(8))) short bf16x8;   // MFMA A/B frag (4 VGPR)
typedef __attribute__((ext_vector_type(4))) float f32x4;    // MFMA C/D frag
typedef __attribute__((ext_vector_type(8))) unsigned short us8;

__device__ __forceinline__ float bf2f(unsigned short u) {
  return __uint_as_float(((unsigned int)u) << 16);
}
__device__ __forceinline__ unsigned short f2bf(float f) {
  unsigned int u = __float_as_uint(f);
  u += 0x7fffu + ((u >> 16) & 1u);
  return (unsigned short)(u >> 16);
}
__device__ __forceinline__ float blo(unsigned int v) { return __uint_as_float(v << 16); }
__device__ __forceinline__ float bhi(unsigned int v) { return __uint_as_float(v & 0xffff0000u); }
__device__ __forceinline__ unsigned int cvt_pk_bf16(float lo, float hi) {
  unsigned int r;
  asm("v_cvt_pk_bf16_f32 %0, %1, %2" : "=v"(r) : "v"(lo), "v"(hi));
  return r;   // low ushort = bf16(lo), high ushort = bf16(hi)  [RNE]
}
__device__ __forceinline__ void gld_lds16(const unsigned short* g, unsigned short* l) {
  __builtin_amdgcn_global_load_lds(
      (const __attribute__((address_space(1))) unsigned int*)g,
      (__attribute__((address_space(3))) unsigned int*)l, 16, 0, 0);
}

// ---------------------------------------------------------------------------
// Fused convert + weight prep (round-7 verbatim — proven).
// ---------------------------------------------------------------------------
__global__ __launch_bounds__(256) void convprep(
    const float* __restrict__ a, const float* __restrict__ b,
    unsigned short* __restrict__ da, unsigned short* __restrict__ db,
    const float* __restrict__ Woff, const float* __restrict__ Wattn,
    const float* __restrict__ Wval, const float* __restrict__ Wout,
    unsigned short* __restrict__ BtOff, unsigned short* __restrict__ BtAttn,
    unsigned short* __restrict__ BtVal, unsigned short* __restrict__ BtOut)
{
  const int bid = blockIdx.x;
  if (bid < 10880) {
    const int tid = bid * 256 + threadIdx.x;
    const int half = kM * 32;
    const float* src; unsigned short* dst; int id;
    if (tid < half) { src = a; dst = da; id = tid; }
    else            { src = b; dst = db; id = tid - half; }
    const int m = id >> 5;
    const int kb = (id & 31) * 8;
    const float4 x0 = *(const float4*)&src[(size_t)m * 256 + kb];
    const float4 x1 = *(const float4*)&src[(size_t)m * 256 + kb + 4];
    us8 o;
    o[0] = f2bf(x0.x); o[1] = f2bf(x0.y); o[2] = f2bf(x0.z); o[3] = f2bf(x0.w);
    o[4] = f2bf(x1.x); o[5] = f2bf(x1.y); o[6] = f2bf(x1.z); o[7] = f2bf(x1.w);
    *(us8*)&dst[(size_t)m * 256 + (kb ^ ((m & 7) << 3))] = o;
  } else {
    const int tid = (bid - 10880) * 256 + threadIdx.x;   // 896 rows * 32
    const int r = tid >> 5;
    const int kb = (tid & 31) * 8;
    const float* W; unsigned short* Bt; int n, Nn;
    if (r < 256)      { W = Woff;  Bt = BtOff;  n = r;       Nn = 256; }
    else if (r < 384) { W = Wattn; Bt = BtAttn; n = r - 256; Nn = 128; }
    else if (r < 640) { W = Wval;  Bt = BtVal;  n = r - 384; Nn = 256; }
    else              { W = Wout;  Bt = BtOut;  n = r - 640; Nn = 256; }
    us8 o;
#pragma unroll
    for (int i = 0; i < 8; ++i) o[i] = f2bf(W[(size_t)(kb + i) * Nn + n]);
    *(us8*)&Bt[(size_t)n * 256 + (kb ^ ((n & 7) << 3))] = o;
  }
}

// ---------------------------------------------------------------------------
// Shared MFMA tile core (round-7 verbatim — proven).
// ---------------------------------------------------------------------------
__device__ __forceinline__ void mfma_tile_256(
    const unsigned short* __restrict__ A, const unsigned short* __restrict__ Bt,
    int m0, int n0, int t, unsigned short* As, unsigned short* Bs,
    f32x4 (&acc)[4][4])
{
  const int w = t >> 6, l = t & 63;
  const int wm = w >> 1, wn = w & 1;
  const int srow = l >> 3;
  const int skb  = (l & 7) * 8;

  for (int kt = 0; kt < 256; kt += 64) {
#pragma unroll
    for (int i = 0; i < 4; ++i) {
      const int c = i * 4 + w;
      const int row = c * 8 + srow;
      gld_lds16(A + (size_t)(m0 + row) * 256 + kt + skb, &As[c * 512]);
    }
#pragma unroll
    for (int i = 0; i < 4; ++i) {
      const int c = i * 4 + w;
      const int row = c * 8 + srow;
      gld_lds16(Bt + (size_t)(n0 + row) * 256 + kt + skb, &Bs[c * 512]);
    }
    __syncthreads();

#pragma unroll
    for (int s = 0; s < 2; ++s) {
      bf16x8 afr[4], bfr[4];
      const int kf = s * 32 + ((l >> 4) * 8);
#pragma unroll
      for (int i = 0; i < 4; ++i) {
        const int row = wm * 64 + i * 16 + (l & 15);
        afr[i] = *(const bf16x8*)&As[row * 64 + (kf ^ ((row & 7) << 3))];
      }
#pragma unroll
      for (int j = 0; j < 4; ++j) {
        const int col = wn * 64 + j * 16 + (l & 15);
        bfr[j] = *(const bf16x8*)&Bs[col * 64 + (kf ^ ((col & 7) << 3))];
      }
#pragma unroll
      for (int i = 0; i < 4; ++i)
#pragma unroll
        for (int j = 0; j < 4; ++j)
          acc[i][j] = __builtin_amdgcn_mfma_f32_16x16x32_bf16(afr[i], bfr[j], acc[i][j], 0, 0, 0);
    }
    __syncthreads();
  }
}

// ---------------------------------------------------------------------------
// Lead GEMM (round-7 verbatim — proven).
// ---------------------------------------------------------------------------
__global__ __launch_bounds__(256) void gemm_lead(
    const unsigned short* __restrict__ in_bf,
    const unsigned short* __restrict__ s_bf,
    const unsigned short* __restrict__ BtOA,
    const unsigned short* __restrict__ BtVal,
    const float* __restrict__ b_off, const float* __restrict__ b_attn,
    const float* __restrict__ b_val,
    unsigned short* __restrict__ off_hm,
    unsigned short* __restrict__ attn_hm,
    unsigned short* __restrict__ val_hm)
{
  const int bid = blockIdx.x;
  const int x = bid & 7;
  const int slot = bid >> 3;
  int mode, nt, mh;
  if (slot < 129) { mode = 0; nt = slot % 3; mh = slot / 3; }
  else            { mode = 1; const int s2 = slot - 129; nt = s2 % 2; mh = s2 / 2; }
  const int m = mh * 8 + x;
  if (m >= kMT) return;
  const int m0 = m * 128, n0 = nt * 128;

  __shared__ unsigned short As[128 * 64];
  __shared__ unsigned short Bs[128 * 64];
  const int t = threadIdx.x;

  f32x4 acc[4][4] = {};
  mfma_tile_256(mode ? s_bf : in_bf, mode ? BtVal : BtOA, m0, n0, t, As, Bs, acc);

  const int w = t >> 6, l = t & 63;
  const int wm = w >> 1, wn = w & 1;
  const int lr = l >> 4;
#pragma unroll
  for (int j = 0; j < 4; ++j) {
    const int col = n0 + wn * 64 + j * 16 + (l & 15);
    const float bv = mode ? b_val[col] : (col < 256 ? b_off[col] : b_attn[col - 256]);
#pragma unroll
    for (int i = 0; i < 4; ++i) {
      const int rbase = m0 + wm * 64 + i * 16 + lr * 4;
#pragma unroll
      for (int r = 0; r < 4; ++r) {
        const float v = acc[i][j][r] + bv;
        const int row = rbase + r;
        if (mode == 1) {          // value head-major [16][kS][32]
          const int bb = row >= kS;
          const int s2 = row - bb * kS;
          val_hm[((size_t)(bb * 8 + (col >> 5)) * kS + s2) * 32 + (col & 31)] = f2bf(v);
        } else if (col < 256) {   // off head-major [8][kM][32]
          off_hm[((size_t)(col >> 5) * kM + row) * 32 + (col & 31)] = f2bf(v);
        } else {                  // attn head-major [8][kM][16]
          const int c2 = col - 256;
          attn_hm[((size_t)(c2 >> 4) * kM + row) * 16 + (c2 & 15)] = f2bf(v);
        }
      }
    }
  }
}

// ---------------------------------------------------------------------------
// Output GEMM (round-7 verbatim — proven).
// ---------------------------------------------------------------------------
__global__ __launch_bounds__(256) void gemm_out(
    const unsigned short* __restrict__ wgt,
    const unsigned short* __restrict__ BtOut,
    const float* __restrict__ b_out,
    float* __restrict__ out)
{
  const int bid = blockIdx.x;
  const int x = bid & 7;
  const int slot = bid >> 3;
  const int nt = slot % 2;
  const int mh = slot / 2;
  const int m = mh * 8 + x;
  if (m >= kMT) return;
  const int m0 = m * 128, n0 = nt * 128;

  __shared__ unsigned short As[128 * 64];
  __shared__ unsigned short Bs[128 * 64];
  const int t = threadIdx.x;

  f32x4 acc[4][4] = {};
  mfma_tile_256(wgt, BtOut, m0, n0, t, As, Bs, acc);

  const int w = t >> 6, l = t & 63;
  const int wm = w >> 1, wn = w & 1;
  const int lr = l >> 4;
#pragma unroll
  for (int j = 0; j < 4; ++j) {
    const int col = n0 + wn * 64 + j * 16 + (l & 15);
    const float bv = b_out[col];
#pragma unroll
    for (int i = 0; i < 4; ++i) {
      const int rbase = m0 + wm * 64 + i * 16 + lr * 4;
#pragma unroll
      for (int r = 0; r < 4; ++r)
        out[(size_t)(rbase + r) * 256 + col] = acc[i][j][r] + bv;
    }
  }
}

// ---------------------------------------------------------------------------
// MSDA core — ROUND-7 VERBATIM (measured 72.2 us; best of 4 structural
// variants tried r7/r8/r10/r11). L2-random-row bandwidth-bound: moves the
// algorithmically-required 1.43 GB of corner reads at ~20 TB/s (57% of the
// sequential L2 ceiling) with fully-random row addresses — the floor for
// this op on this chip.
// ---------------------------------------------------------------------------
__global__ __launch_bounds__(256, 4) void msda_kernel(
    const unsigned short* __restrict__ off_hm,   // [8][kM][32] bf16 head-major
    const unsigned short* __restrict__ attn_hm,  // [8][kM][16] bf16 head-major
    const unsigned short* __restrict__ val_bf,   // [16][kS][32] bf16 head-major
    const float* __restrict__ priors,            // [kM][8]
    unsigned short* __restrict__ wgt)            // [kM][256] bf16 swizzled
{
  __shared__ int s_rec[16 * 136];
  const int bid = blockIdx.x;
  const int plane = bid & 15;          // b*8 + h
  const int chunk = bid >> 4;
  const int b = plane >> 3, h = plane & 7;
  const int t = threadIdx.x;
  const int ql = t >> 4;
  const int q = b * kN + chunk * 16 + ql;

  { // ---- phase 1 ----
    const int j = t & 15;
    const int lv = j >> 2;

    const float lgt = bf2f(attn_hm[((size_t)h * kM + q) * 16 + j]);
    float mx = lgt;
#pragma unroll
    for (int m = 8; m; m >>= 1) mx = fmaxf(mx, __shfl_xor(mx, m, 16));
    const float p = __expf(lgt - mx);
    float sum = p;
#pragma unroll
    for (int m = 8; m; m >>= 1) sum += __shfl_xor(sum, m, 16);
    const float wN = p / sum;

    const unsigned int oo = *(const unsigned int*)&off_hm[((size_t)h * kM + q) * 32 + j * 2];
    const float ox = blo(oo);
    const float oy = bhi(oo);
    const float2 pr = *(const float2*)&priors[(size_t)q * 8 + lv * 2];

    const int Wl = 128 >> lv;
    const float fW = (float)Wl;
    const float lx = fmaf(pr.x, fW, ox) - 0.5f;
    const float ly = fmaf(pr.y, fW, oy) - 0.5f;
    const float x0f = floorf(lx), y0f = floorf(ly);
    const float wx1 = lx - x0f, wy1 = ly - y0f;
    const float wx0 = 1.f - wx1, wy0 = 1.f - wy1;
    const int x0 = (int)x0f, y0 = (int)y0f;
    const int start = (int)((0x5400500040000000ull >> (16 * lv)) & 0xffff); // {0,16384,20480,21504}

    const bool vx0 = (x0 >= 0) & (x0 < Wl);
    const bool vx1 = (x0 + 1 >= 0) & (x0 + 1 < Wl);
    const bool vy0 = (y0 >= 0) & (y0 < Wl);
    const bool vy1 = (y0 + 1 >= 0) & (y0 + 1 < Wl);
    const int xc0 = min(max(x0, 0), Wl - 1);
    const int xc1 = min(max(x0 + 1, 0), Wl - 1);
    const int yc0 = min(max(y0, 0), Wl - 1);
    const int yc1 = min(max(y0 + 1, 0), Wl - 1);

    const int rt = start + yc0 * Wl;   // row bases (elements)
    const int rb = start + yc1 * Wl;

    int4 r0, r1;
    r0.x = (rt + xc0) * 64; r0.y = __float_as_int((vx0 & vy0) ? wN * wx0 * wy0 : 0.f);
    r0.z = (rt + xc1) * 64; r0.w = __float_as_int((vx1 & vy0) ? wN * wx1 * wy0 : 0.f);
    r1.x = (rb + xc0) * 64; r1.y = __float_as_int((vx0 & vy1) ? wN * wx0 * wy1 : 0.f);
    r1.z = (rb + xc1) * 64; r1.w = __float_as_int((vx1 & vy1) ? wN * wx1 * wy1 : 0.f);

    const int base = ql * 136 + j * 8;
    *(int4*)&s_rec[base] = r0;
    *(int4*)&s_rec[base + 4] = r1;
  }
  __syncthreads();

  // ---- phase 2 (MLP-batched, compiler-scheduled) ----
  const int lane = t & 15;
  const int c = lane >> 2;        // corner: 0=TL 1=TR 2=BL 3=BR
  const int k = lane & 3;         // 16B chunk (8 channels)
  const char* plane_base = (const char*)val_bf + (size_t)plane * kS * 64 + k * 16;
  const int* rp = &s_rec[ql * 136 + c * 2];

  float a0 = 0.f, a1 = 0.f, a2 = 0.f, a3 = 0.f;
  float a4 = 0.f, a5 = 0.f, a6 = 0.f, a7 = 0.f;
#pragma unroll
  for (int B = 0; B < 2; ++B) {
    int2 r[8];
#pragma unroll
    for (int j = 0; j < 8; ++j) r[j] = *(const int2*)&rp[(B * 8 + j) * 8];
    uint4 v[8];
#pragma unroll
    for (int j = 0; j < 8; ++j) v[j] = *(const uint4*)(plane_base + r[j].x);
#pragma unroll
    for (int j = 0; j < 8; ++j) {
      const float w = __int_as_float(r[j].y);
      a0 = fmaf(w, blo(v[j].x), a0); a1 = fmaf(w, bhi(v[j].x), a1);
      a2 = fmaf(w, blo(v[j].y), a2); a3 = fmaf(w, bhi(v[j].y), a3);
      a4 = fmaf(w, blo(v[j].z), a4); a5 = fmaf(w, bhi(v[j].z), a5);
      a6 = fmaf(w, blo(v[j].w), a6); a7 = fmaf(w, bhi(v[j].w), a7);
    }
  }

  // fold the 4 corners (lane bits 2-3)
#pragma unroll
  for (int m = 4; m <= 8; m <<= 1) {
    a0 += __shfl_xor(a0, m); a1 += __shfl_xor(a1, m);
    a2 += __shfl_xor(a2, m); a3 += __shfl_xor(a3, m);
    a4 += __shfl_xor(a4, m); a5 += __shfl_xor(a5, m);
    a6 += __shfl_xor(a6, m); a7 += __shfl_xor(a7, m);
  }

  if (c == 0) {
    const int c0 = h * 32 + k * 8;                    // ushort index in row
    const int dst = c0 ^ ((q & 7) << 3);
    uint4 o;
    o.x = cvt_pk_bf16(a0, a1);
    o.y = cvt_pk_bf16(a2, a3);
    o.z = cvt_pk_bf16(a4, a5);
    o.w = cvt_pk_bf16(a6, a7);
    *(uint4*)&wgt[(size_t)q * 256 + dst] = o;
  }
}

// ---------------------------------------------------------------------------
// launch
// ---------------------------------------------------------------------------
extern "C" void kernel_launch(void* const* d_in, const int* in_sizes, int n_in,
                              void* d_out, int out_size, void* d_ws, size_t ws_size,
                              hipStream_t stream) {
  const float* in_feats = (const float*)d_in[0];
  const float* priors   = (const float*)d_in[1];
  const float* sfeats   = (const float*)d_in[2];
  const float* W_off  = (const float*)d_in[5];
  const float* b_off  = (const float*)d_in[6];
  const float* W_attn = (const float*)d_in[7];
  const float* b_attn = (const float*)d_in[8];
  const float* W_val  = (const float*)d_in[9];
  const float* b_val  = (const float*)d_in[10];
  const float* W_out  = (const float*)d_in[11];
  const float* b_out  = (const float*)d_in[12];
  float* out = (float*)d_out;

  // workspace (bf16 ushorts), ~123 MB
  unsigned short* in_bf   = (unsigned short*)d_ws;          // kM*256 (swizzled)
  unsigned short* s_bf    = in_bf   + (size_t)kM * 256;     // kM*256 (swizzled)
  unsigned short* off_hm  = s_bf    + (size_t)kM * 256;     // [8][kM][32]
  unsigned short* attn_hm = off_hm  + (size_t)kM * 256;     // [8][kM][16]
  unsigned short* val_hm  = attn_hm + (size_t)kM * 128;     // [16][kS][32]
  unsigned short* wgt_bf  = val_hm  + (size_t)kM * 256;     // [kM][256] swizzled
  unsigned short* BtOff   = wgt_bf  + (size_t)kM * 256;     // 256*256 (BtOA rows 0-255)
  unsigned short* BtAttn  = BtOff   + 256 * 256;            // 128*256 (BtOA rows 256-383)
  unsigned short* BtVal   = BtAttn  + 128 * 256;            // 256*256
  unsigned short* BtOut   = BtVal   + 256 * 256;            // 256*256

  const dim3 blk(256);

  convprep<<<dim3(10992), blk, 0, stream>>>(
      in_feats, sfeats, in_bf, s_bf,
      W_off, W_attn, W_val, W_out, BtOff, BtAttn, BtVal, BtOut);

  gemm_lead<<<dim3(8 * 215), blk, 0, stream>>>(
      in_bf, s_bf, BtOff, BtVal, b_off, b_attn, b_val, off_hm, attn_hm, val_hm);

  msda_kernel<<<dim3(kM / 2), blk, 0, stream>>>(off_hm, attn_hm, val_hm, priors, wgt_bf);

  gemm_out<<<dim3(8 * 2 * 43), blk, 0, stream>>>(wgt_bf, BtOut, b_out, out);
}